// Round 14
// baseline (355.073 us; speedup 1.0000x reference)
//
#include <hip/hip_runtime.h>
#include <hip/hip_bf16.h>

typedef __bf16 bf16x8 __attribute__((ext_vector_type(8)));
typedef float f32x4 __attribute__((ext_vector_type(4)));
typedef __hip_bfloat16 bf16;

#define B_ 4
#define S_ 2048
#define D_ 1024
#define H_ 16
#define HD_ 64

__device__ __forceinline__ void gload16(const bf16* g, bf16* l) {
  __builtin_amdgcn_global_load_lds(
      (const __attribute__((address_space(1))) unsigned int*)g,
      (__attribute__((address_space(3))) unsigned int*)l, 16, 0, 0);
}

#define MFMA16(a, b, c) __builtin_amdgcn_mfma_f32_16x16x32_bf16((a), (b), (c), 0, 0, 0)

// ---------------------------------------------------------------- cvt f32->bf16 (fused x, w_qkv, w_out)
#define NX_ (B_ * S_ * D_)
#define NW1_ (3 * D_ * D_)
#define NW2_ (D_ * D_)
__global__ __launch_bounds__(256) void k_cvt3(const float* __restrict__ x,
                                              const float* __restrict__ w1,
                                              const float* __restrict__ w2,
                                              bf16* __restrict__ ox,
                                              bf16* __restrict__ o1,
                                              bf16* __restrict__ o2) {
  int i = (blockIdx.x * 256 + threadIdx.x) * 4;
  const float* in;
  bf16* out;
  if (i < NX_) {
    in = x; out = ox;
  } else if (i < NX_ + NW1_) {
    in = w1; out = o1; i -= NX_;
  } else {
    in = w2; out = o2; i -= NX_ + NW1_;
  }
  float4 v = *reinterpret_cast<const float4*>(in + i);
  alignas(8) bf16 t[4];
  t[0] = __float2bfloat16(v.x);
  t[1] = __float2bfloat16(v.y);
  t[2] = __float2bfloat16(v.z);
  t[3] = __float2bfloat16(v.w);
  *reinterpret_cast<uint2*>(out + i) = *reinterpret_cast<uint2*>(t);
}

// ---------------------------------------------------------------- QKV GEMM (R13: interleaved counted-vmcnt)
__global__ __launch_bounds__(512) void k_qkv(const bf16* __restrict__ X,
                                             const bf16* __restrict__ W,
                                             bf16* __restrict__ Qw,
                                             bf16* __restrict__ Kw,
                                             bf16* __restrict__ Vtw) {
  __shared__ bf16 Al[2][128 * 64];  // 32 KB
  __shared__ bf16 Bl[2][256 * 64];  // 64 KB
  const int tid = threadIdx.x;
  const int wid = tid >> 6, lane = tid & 63, col = lane & 15, g = lane >> 4;
  const int wr = wid >> 2, wc = wid & 3;
  const int m0 = blockIdx.x * 128, n0 = blockIdx.y * 256;
  const int srow = tid >> 3;                 // 0..63
  const int scol = (tid & 7) * 8;
  const int csrc = scol ^ ((srow & 7) * 8);  // pre-swizzled source col
  const bf16* ga = X + (size_t)(m0 + srow) * 1024 + csrc;
  const bf16* gb = W + (size_t)(n0 + srow) * 1024 + csrc;
  const int ldst = srow * 64 + scol;         // linear LDS dest
  const int rsw = (col & 7) * 8;
  f32x4 acc[4][4] = {};
#define QKV_STAGE_ALL(buf, k0)                               \
  do {                                                       \
    gload16(ga + (k0), &Al[buf][ldst]);                      \
    gload16(ga + (k0) + 64 * 1024, &Al[buf][ldst + 4096]);   \
    gload16(gb + (k0), &Bl[buf][ldst]);                      \
    gload16(gb + (k0) + 64 * 1024, &Bl[buf][ldst + 4096]);   \
    gload16(gb + (k0) + 128 * 1024, &Bl[buf][ldst + 8192]);  \
    gload16(gb + (k0) + 192 * 1024, &Bl[buf][ldst + 12288]); \
  } while (0)
  QKV_STAGE_ALL(0, 0);
  QKV_STAGE_ALL(1, 64);
  for (int kt = 0; kt < 16; ++kt) {
    const int c = kt & 1;
    if (kt < 15)
      asm volatile("s_waitcnt vmcnt(6)" ::: "memory");
    else
      asm volatile("s_waitcnt vmcnt(0)" ::: "memory");
    __builtin_amdgcn_s_barrier();  // tile kt landed for all waves
    const bf16* Ac = Al[c];
    const bf16* Bc = Bl[c];
    bf16x8 af[2][4], bfr[2][4];
#pragma unroll
    for (int kk = 0; kk < 2; ++kk) {
      const int ce = (kk * 32 + g * 8) ^ rsw;
#pragma unroll
      for (int m = 0; m < 4; ++m)
        af[kk][m] =
            *reinterpret_cast<const bf16x8*>(&Ac[(wr * 64 + m * 16 + col) * 64 + ce]);
#pragma unroll
      for (int n = 0; n < 4; ++n)
        bfr[kk][n] =
            *reinterpret_cast<const bf16x8*>(&Bc[(wc * 64 + n * 16 + col) * 64 + ce]);
    }
    __builtin_amdgcn_s_setprio(1);
#pragma unroll
    for (int m = 0; m < 4; ++m) {
      acc[m][0] = MFMA16(af[0][m], bfr[0][0], acc[m][0]);
      acc[m][1] = MFMA16(af[0][m], bfr[0][1], acc[m][1]);
    }
    __builtin_amdgcn_s_setprio(0);
    asm volatile("s_waitcnt lgkmcnt(0)" ::: "memory");
    __builtin_amdgcn_sched_barrier(0);
    __builtin_amdgcn_s_barrier();  // all waves' reads of buf c complete -> free
    const bool more = (kt + 2 < 16);
    const int k2 = (kt + 2) * 64;
    if (more) {
      gload16(ga + k2, &Al[c][ldst]);
      gload16(ga + k2 + 64 * 1024, &Al[c][ldst + 4096]);
    }
    __builtin_amdgcn_s_setprio(1);
#pragma unroll
    for (int m = 0; m < 4; ++m) {
      acc[m][2] = MFMA16(af[0][m], bfr[0][2], acc[m][2]);
      acc[m][3] = MFMA16(af[0][m], bfr[0][3], acc[m][3]);
    }
    __builtin_amdgcn_s_setprio(0);
    if (more) {
      gload16(gb + k2, &Bl[c][ldst]);
      gload16(gb + k2 + 64 * 1024, &Bl[c][ldst + 4096]);
    }
    __builtin_amdgcn_s_setprio(1);
#pragma unroll
    for (int m = 0; m < 4; ++m) {
      acc[m][0] = MFMA16(af[1][m], bfr[1][0], acc[m][0]);
      acc[m][1] = MFMA16(af[1][m], bfr[1][1], acc[m][1]);
    }
    __builtin_amdgcn_s_setprio(0);
    if (more) {
      gload16(gb + k2 + 128 * 1024, &Bl[c][ldst + 8192]);
      gload16(gb + k2 + 192 * 1024, &Bl[c][ldst + 12288]);
    }
    __builtin_amdgcn_s_setprio(1);
#pragma unroll
    for (int m = 0; m < 4; ++m) {
      acc[m][2] = MFMA16(af[1][m], bfr[1][2], acc[m][2]);
      acc[m][3] = MFMA16(af[1][m], bfr[1][3], acc[m][3]);
    }
    __builtin_amdgcn_s_setprio(0);
  }
#undef QKV_STAGE_ALL
  const int e0 = n0 + wc * 64;
  const int which = e0 >> 10;
  const int h = (e0 >> 6) & 15;
  if (which == 2) {
#pragma unroll
    for (int m = 0; m < 4; ++m) {
      int mg = m0 + wr * 64 + m * 16 + g * 4;
      int b = mg >> 11, s = mg & 2047;
#pragma unroll
      for (int n = 0; n < 4; ++n) {
        int d = n * 16 + col;
        alignas(8) bf16 t[4];
#pragma unroll
        for (int r = 0; r < 4; ++r) t[r] = __float2bfloat16(acc[m][n][r]);
        *reinterpret_cast<uint2*>(&Vtw[((size_t)((b * 16 + h) * 64 + d) << 11) + s]) =
            *reinterpret_cast<uint2*>(t);
      }
    }
  } else {
    bf16* dst = which ? Kw : Qw;
    const float scale = which ? 1.0f : 0.18033688011112042f;  // 0.125*log2(e)
    const float fexp = -2.0f * 13.287712379549449f / 64.0f;
#pragma unroll
    for (int i = 0; i < 2; ++i) {
      int dlo = i * 16 + col;
      float invf = exp2f(fexp * (float)dlo);
#pragma unroll
      for (int m = 0; m < 4; ++m) {
        int mg = m0 + wr * 64 + m * 16 + g * 4;
        int b = mg >> 11;
        size_t rb = (size_t)(b * 16 + h) << 11;
#pragma unroll
        for (int r = 0; r < 4; ++r) {
          int s = (mg + r) & 2047;
          float sn, cs;
          __sincosf((float)s * invf, &sn, &cs);
          float lo = acc[m][i][r] * scale, hi = acc[m][i + 2][r] * scale;
          dst[((rb + s) << 6) + dlo] = __float2bfloat16(lo * cs - hi * sn);
          dst[((rb + s) << 6) + dlo + 32] = __float2bfloat16(hi * cs + lo * sn);
        }
      }
    }
  }
}

// ---------------------------------------------------------------- flash attention (barrier-free)
// K/V/Q fragments read DIRECTLY from global (L1/L2-resident: 512KB per bh;
// each 64-lane frag load = one contiguous 2KB window -> cache-friendly).
// No LDS staging, no memory barriers; only a raw pacing s_barrier per tile
// keeps the 8 waves on the same K-tile for 8x L1 reuse. LDS = P buffer only
// (wave-private rows, 18.4KB -> 4 blocks/CU). Mask only at kt==ktmax
// (interior tiles provably unmasked). No-max exp2 softmax; QTMAP balance.
__global__ __launch_bounds__(512) void k_attn(const bf16* __restrict__ Q,
                                              const bf16* __restrict__ K,
                                              const bf16* __restrict__ Vt,
                                              bf16* __restrict__ AO) {
  __shared__ bf16 Pl[128][72];  // per-wave P rows
  const int tid = threadIdx.x;
  const int wave = tid >> 6, lane = tid & 63, col = lane & 15, g = lane >> 4;
  const int bh = blockIdx.x;
  const size_t base = (size_t)bh << 17;
  const int b = bh >> 4, h = bh & 15;
  // y -> qt mapping: quartets {y,y+4,y+8,y+12} sum to 30 => equal per-CU work
  const int yy = blockIdx.y, a = yy >> 2, r_ = yy & 3;
  const int qt = (a == 0) ? (15 - r_) : (a == 1) ? (8 + (r_ ^ 2)) : (a == 2) ? (4 + (r_ ^ 1)) : r_;
  const int q0 = qt * 128;
  const int qw = q0 + wave * 16;
  const int q = qw + col;  // this lane's q-row
  // fragment base pointers (lane-dependent)
  const bf16* Qp = Q + base + (size_t)q * 64 + g * 8;
  const bf16* Kp = K + base + (size_t)col * 64 + g * 8;
  const bf16* Vp = Vt + base + (size_t)col * 2048 + g * 8;
  bf16x8 qf[2];
  qf[0] = *reinterpret_cast<const bf16x8*>(Qp);
  qf[1] = *reinterpret_cast<const bf16x8*>(Qp + 32);
  const int ktlim = 2 * qt + 1;      // block-wide last tile (incl.)
  const int ktmax = (qw + 15) >> 6;  // this wave's last (diagonal) tile
  float l_s = 0.0f;
  f32x4 o[4] = {};
  for (int kt = 0; kt <= ktlim; ++kt) {
    if (kt <= ktmax) {
      const int k0 = kt * 64;
      const bool dmask = (kt == ktmax);
      const bf16* Kt = Kp + (size_t)k0 * 64;
      __builtin_amdgcn_s_setprio(1);
#pragma unroll
      for (int n = 0; n < 4; ++n) {
        f32x4 s = {};
#pragma unroll
        for (int kk = 0; kk < 2; ++kk) {
          bf16x8 kf = *reinterpret_cast<const bf16x8*>(Kt + n * 1024 + kk * 32);
          s = MFMA16(kf, qf[kk], s);
        }
        if (dmask) {
#pragma unroll
          for (int r = 0; r < 4; ++r)
            if (k0 + n * 16 + g * 4 + r > q) s[r] = -3e38f;
        }
        alignas(8) bf16 t[4];
#pragma unroll
        for (int r = 0; r < 4; ++r) {
          float p = exp2f(s[r]);
          l_s += p;
          t[r] = __float2bfloat16(p);
        }
        *reinterpret_cast<uint2*>(&Pl[wave * 16 + col][n * 16 + g * 4]) =
            *reinterpret_cast<uint2*>(t);
      }
      // O += P V   (P wave-private; V fragments straight from L1/L2)
#pragma unroll
      for (int kk = 0; kk < 2; ++kk) {
        bf16x8 pf =
            *reinterpret_cast<const bf16x8*>(&Pl[wave * 16 + col][g * 8 + kk * 32]);
#pragma unroll
        for (int n2 = 0; n2 < 4; ++n2) {
          bf16x8 vf =
              *reinterpret_cast<const bf16x8*>(Vp + n2 * 32768 + k0 + kk * 32);
          o[n2] = MFMA16(pf, vf, o[n2]);
        }
      }
      __builtin_amdgcn_s_setprio(0);
    }
    __builtin_amdgcn_s_barrier();  // pacing only: keeps waves on same tile (L1 reuse)
  }
  l_s += __shfl_xor(l_s, 16);
  l_s += __shfl_xor(l_s, 32);
#pragma unroll
  for (int r = 0; r < 4; ++r) {
    float inv = 1.0f / __shfl(l_s, (lane & 48) | (g * 4 + r));
    int s = qw + g * 4 + r;
#pragma unroll
    for (int n2 = 0; n2 < 4; ++n2)
      AO[((size_t)(b * 2048 + s) << 10) + h * 64 + n2 * 16 + col] =
          __float2bfloat16(o[n2][r] * inv);
  }
}

// ---------------------------------------------------------------- out projection (R13: interleaved counted-vmcnt)
__global__ __launch_bounds__(512) void k_outproj(const bf16* __restrict__ A,
                                                 const bf16* __restrict__ W,
                                                 float* __restrict__ OUT) {
  __shared__ bf16 Al[2][128 * 64];
  __shared__ bf16 Bl[2][256 * 64];
  const int tid = threadIdx.x;
  const int wid = tid >> 6, lane = tid & 63, col = lane & 15, g = lane >> 4;
  const int wr = wid >> 2, wc = wid & 3;
  const int m0 = blockIdx.x * 128, n0 = blockIdx.y * 256;
  const int srow = tid >> 3;
  const int scol = (tid & 7) * 8;
  const int csrc = scol ^ ((srow & 7) * 8);
  const bf16* ga = A + (size_t)(m0 + srow) * 1024 + csrc;
  const bf16* gb = W + (size_t)(n0 + srow) * 1024 + csrc;
  const int ldst = srow * 64 + scol;
  const int rsw = (col & 7) * 8;
  f32x4 acc[4][4] = {};
#define OP_STAGE_ALL(buf, k0)                                \
  do {                                                       \
    gload16(ga + (k0), &Al[buf][ldst]);                      \
    gload16(ga + (k0) + 64 * 1024, &Al[buf][ldst + 4096]);   \
    gload16(gb + (k0), &Bl[buf][ldst]);                      \
    gload16(gb + (k0) + 64 * 1024, &Bl[buf][ldst + 4096]);   \
    gload16(gb + (k0) + 128 * 1024, &Bl[buf][ldst + 8192]);  \
    gload16(gb + (k0) + 192 * 1024, &Bl[buf][ldst + 12288]); \
  } while (0)
  OP_STAGE_ALL(0, 0);
  OP_STAGE_ALL(1, 64);
  for (int kt = 0; kt < 16; ++kt) {
    const int c = kt & 1;
    if (kt < 15)
      asm volatile("s_waitcnt vmcnt(6)" ::: "memory");
    else
      asm volatile("s_waitcnt vmcnt(0)" ::: "memory");
    __builtin_amdgcn_s_barrier();
    const bf16* Ac = Al[c];
    const bf16* Bc = Bl[c];
    bf16x8 af[2][4], bfr[2][4];
#pragma unroll
    for (int kk = 0; kk < 2; ++kk) {
      const int ce = (kk * 32 + g * 8) ^ rsw;
#pragma unroll
      for (int m = 0; m < 4; ++m)
        af[kk][m] =
            *reinterpret_cast<const bf16x8*>(&Ac[(wr * 64 + m * 16 + col) * 64 + ce]);
#pragma unroll
      for (int n = 0; n < 4; ++n)
        bfr[kk][n] =
            *reinterpret_cast<const bf16x8*>(&Bc[(wc * 64 + n * 16 + col) * 64 + ce]);
    }
    __builtin_amdgcn_s_setprio(1);
#pragma unroll
    for (int m = 0; m < 4; ++m) {
      acc[m][0] = MFMA16(af[0][m], bfr[0][0], acc[m][0]);
      acc[m][1] = MFMA16(af[0][m], bfr[0][1], acc[m][1]);
    }
    __builtin_amdgcn_s_setprio(0);
    asm volatile("s_waitcnt lgkmcnt(0)" ::: "memory");
    __builtin_amdgcn_sched_barrier(0);
    __builtin_amdgcn_s_barrier();
    const bool more = (kt + 2 < 16);
    const int k2 = (kt + 2) * 64;
    if (more) {
      gload16(ga + k2, &Al[c][ldst]);
      gload16(ga + k2 + 64 * 1024, &Al[c][ldst + 4096]);
    }
    __builtin_amdgcn_s_setprio(1);
#pragma unroll
    for (int m = 0; m < 4; ++m) {
      acc[m][2] = MFMA16(af[0][m], bfr[0][2], acc[m][2]);
      acc[m][3] = MFMA16(af[0][m], bfr[0][3], acc[m][3]);
    }
    __builtin_amdgcn_s_setprio(0);
    if (more) {
      gload16(gb + k2, &Bl[c][ldst]);
      gload16(gb + k2 + 64 * 1024, &Bl[c][ldst + 4096]);
    }
    __builtin_amdgcn_s_setprio(1);
#pragma unroll
    for (int m = 0; m < 4; ++m) {
      acc[m][0] = MFMA16(af[1][m], bfr[1][0], acc[m][0]);
      acc[m][1] = MFMA16(af[1][m], bfr[1][1], acc[m][1]);
    }
    __builtin_amdgcn_s_setprio(0);
    if (more) {
      gload16(gb + k2 + 128 * 1024, &Bl[c][ldst + 8192]);
      gload16(gb + k2 + 192 * 1024, &Bl[c][ldst + 12288]);
    }
    __builtin_amdgcn_s_setprio(1);
#pragma unroll
    for (int m = 0; m < 4; ++m) {
      acc[m][2] = MFMA16(af[1][m], bfr[1][2], acc[m][2]);
      acc[m][3] = MFMA16(af[1][m], bfr[1][3], acc[m][3]);
    }
    __builtin_amdgcn_s_setprio(0);
  }
#undef OP_STAGE_ALL
#pragma unroll
  for (int m = 0; m < 4; ++m)
#pragma unroll
    for (int n = 0; n < 4; ++n)
#pragma unroll
      for (int r = 0; r < 4; ++r)
        OUT[(size_t)(m0 + wr * 64 + m * 16 + g * 4 + r) * 1024 + n0 + wc * 64 + n * 16 +
            col] = acc[m][n][r];
}

// ---------------------------------------------------------------- launcher
extern "C" void kernel_launch(void* const* d_in, const int* in_sizes, int n_in,
                              void* d_out, int out_size, void* d_ws, size_t ws_size,
                              hipStream_t stream) {
  const float* x = (const float*)d_in[0];
  const float* wqkv = (const float*)d_in[1];
  const float* wout = (const float*)d_in[2];
  float* out = (float*)d_out;

  char* ws = (char*)d_ws;
  const size_t SZ_X = (size_t)B_ * S_ * D_ * 2;
  const size_t SZ_WQKV = (size_t)3 * D_ * D_ * 2;
  const size_t SZ_WOUT = (size_t)D_ * D_ * 2;
  const size_t SZ_T = (size_t)B_ * H_ * S_ * HD_ * 2;
  bf16* xb = (bf16*)(ws);
  bf16* wqkvb = (bf16*)(ws + SZ_X);
  bf16* woutb = (bf16*)(ws + SZ_X + SZ_WQKV);
  bf16* qws = (bf16*)(ws + SZ_X + SZ_WQKV + SZ_WOUT);
  bf16* kws = (bf16*)(ws + SZ_X + SZ_WQKV + SZ_WOUT + SZ_T);
  bf16* vtws = (bf16*)(ws + SZ_X + SZ_WQKV + SZ_WOUT + 2 * SZ_T);
  bf16* aob = (bf16*)(ws + SZ_X + SZ_WQKV + SZ_WOUT + 3 * SZ_T);

  const int NTOT4 = (NX_ + NW1_ + NW2_) / 4;
  k_cvt3<<<NTOT4 / 256, 256, 0, stream>>>(x, wqkv, wout, xb, wqkvb, woutb);

  k_qkv<<<dim3(64, 12), 512, 0, stream>>>(xb, wqkvb, qws, kws, vtws);
  k_attn<<<dim3(B_ * H_, 16), 512, 0, stream>>>(qws, kws, vtws, aob);
  k_outproj<<<dim3(64, 4), 512, 0, stream>>>(aob, woutb, out);
}

// Round 15
// 161.901 us; speedup vs baseline: 2.1931x; 2.1931x over previous
//
#include <hip/hip_runtime.h>
#include <hip/hip_bf16.h>

typedef __bf16 bf16x8 __attribute__((ext_vector_type(8)));
typedef float f32x4 __attribute__((ext_vector_type(4)));
typedef __hip_bfloat16 bf16;

#define B_ 4
#define S_ 2048
#define D_ 1024
#define H_ 16
#define HD_ 64

__device__ __forceinline__ void gload16(const bf16* g, bf16* l) {
  __builtin_amdgcn_global_load_lds(
      (const __attribute__((address_space(1))) unsigned int*)g,
      (__attribute__((address_space(3))) unsigned int*)l, 16, 0, 0);
}

#define MFMA16(a, b, c) __builtin_amdgcn_mfma_f32_16x16x32_bf16((a), (b), (c), 0, 0, 0)

// ---------------------------------------------------------------- cvt f32->bf16 (fused x, w_qkv, w_out)
#define NX_ (B_ * S_ * D_)
#define NW1_ (3 * D_ * D_)
#define NW2_ (D_ * D_)
__global__ __launch_bounds__(256) void k_cvt3(const float* __restrict__ x,
                                              const float* __restrict__ w1,
                                              const float* __restrict__ w2,
                                              bf16* __restrict__ ox,
                                              bf16* __restrict__ o1,
                                              bf16* __restrict__ o2) {
  int i = (blockIdx.x * 256 + threadIdx.x) * 4;
  const float* in;
  bf16* out;
  if (i < NX_) {
    in = x; out = ox;
  } else if (i < NX_ + NW1_) {
    in = w1; out = o1; i -= NX_;
  } else {
    in = w2; out = o2; i -= NX_ + NW1_;
  }
  float4 v = *reinterpret_cast<const float4*>(in + i);
  alignas(8) bf16 t[4];
  t[0] = __float2bfloat16(v.x);
  t[1] = __float2bfloat16(v.y);
  t[2] = __float2bfloat16(v.z);
  t[3] = __float2bfloat16(v.w);
  *reinterpret_cast<uint2*>(out + i) = *reinterpret_cast<uint2*>(t);
}

// ---------------------------------------------------------------- QKV GEMM (R13: interleaved counted-vmcnt)
__global__ __launch_bounds__(512) void k_qkv(const bf16* __restrict__ X,
                                             const bf16* __restrict__ W,
                                             bf16* __restrict__ Qw,
                                             bf16* __restrict__ Kw,
                                             bf16* __restrict__ Vtw) {
  __shared__ bf16 Al[2][128 * 64];  // 32 KB
  __shared__ bf16 Bl[2][256 * 64];  // 64 KB
  const int tid = threadIdx.x;
  const int wid = tid >> 6, lane = tid & 63, col = lane & 15, g = lane >> 4;
  const int wr = wid >> 2, wc = wid & 3;
  const int m0 = blockIdx.x * 128, n0 = blockIdx.y * 256;
  const int srow = tid >> 3;                 // 0..63
  const int scol = (tid & 7) * 8;
  const int csrc = scol ^ ((srow & 7) * 8);  // pre-swizzled source col
  const bf16* ga = X + (size_t)(m0 + srow) * 1024 + csrc;
  const bf16* gb = W + (size_t)(n0 + srow) * 1024 + csrc;
  const int ldst = srow * 64 + scol;         // linear LDS dest
  const int rsw = (col & 7) * 8;
  f32x4 acc[4][4] = {};
#define QKV_STAGE_ALL(buf, k0)                               \
  do {                                                       \
    gload16(ga + (k0), &Al[buf][ldst]);                      \
    gload16(ga + (k0) + 64 * 1024, &Al[buf][ldst + 4096]);   \
    gload16(gb + (k0), &Bl[buf][ldst]);                      \
    gload16(gb + (k0) + 64 * 1024, &Bl[buf][ldst + 4096]);   \
    gload16(gb + (k0) + 128 * 1024, &Bl[buf][ldst + 8192]);  \
    gload16(gb + (k0) + 192 * 1024, &Bl[buf][ldst + 12288]); \
  } while (0)
  QKV_STAGE_ALL(0, 0);
  QKV_STAGE_ALL(1, 64);
  for (int kt = 0; kt < 16; ++kt) {
    const int c = kt & 1;
    if (kt < 15)
      asm volatile("s_waitcnt vmcnt(6)" ::: "memory");
    else
      asm volatile("s_waitcnt vmcnt(0)" ::: "memory");
    __builtin_amdgcn_s_barrier();  // tile kt landed for all waves
    const bf16* Ac = Al[c];
    const bf16* Bc = Bl[c];
    bf16x8 af[2][4], bfr[2][4];
#pragma unroll
    for (int kk = 0; kk < 2; ++kk) {
      const int ce = (kk * 32 + g * 8) ^ rsw;
#pragma unroll
      for (int m = 0; m < 4; ++m)
        af[kk][m] =
            *reinterpret_cast<const bf16x8*>(&Ac[(wr * 64 + m * 16 + col) * 64 + ce]);
#pragma unroll
      for (int n = 0; n < 4; ++n)
        bfr[kk][n] =
            *reinterpret_cast<const bf16x8*>(&Bc[(wc * 64 + n * 16 + col) * 64 + ce]);
    }
    __builtin_amdgcn_s_setprio(1);
#pragma unroll
    for (int m = 0; m < 4; ++m) {
      acc[m][0] = MFMA16(af[0][m], bfr[0][0], acc[m][0]);
      acc[m][1] = MFMA16(af[0][m], bfr[0][1], acc[m][1]);
    }
    __builtin_amdgcn_s_setprio(0);
    asm volatile("s_waitcnt lgkmcnt(0)" ::: "memory");
    __builtin_amdgcn_sched_barrier(0);
    __builtin_amdgcn_s_barrier();  // all waves' reads of buf c complete -> free
    const bool more = (kt + 2 < 16);
    const int k2 = (kt + 2) * 64;
    if (more) {
      gload16(ga + k2, &Al[c][ldst]);
      gload16(ga + k2 + 64 * 1024, &Al[c][ldst + 4096]);
    }
    __builtin_amdgcn_s_setprio(1);
#pragma unroll
    for (int m = 0; m < 4; ++m) {
      acc[m][2] = MFMA16(af[0][m], bfr[0][2], acc[m][2]);
      acc[m][3] = MFMA16(af[0][m], bfr[0][3], acc[m][3]);
    }
    __builtin_amdgcn_s_setprio(0);
    if (more) {
      gload16(gb + k2, &Bl[c][ldst]);
      gload16(gb + k2 + 64 * 1024, &Bl[c][ldst + 4096]);
    }
    __builtin_amdgcn_s_setprio(1);
#pragma unroll
    for (int m = 0; m < 4; ++m) {
      acc[m][0] = MFMA16(af[1][m], bfr[1][0], acc[m][0]);
      acc[m][1] = MFMA16(af[1][m], bfr[1][1], acc[m][1]);
    }
    __builtin_amdgcn_s_setprio(0);
    if (more) {
      gload16(gb + k2 + 128 * 1024, &Bl[c][ldst + 8192]);
      gload16(gb + k2 + 192 * 1024, &Bl[c][ldst + 12288]);
    }
    __builtin_amdgcn_s_setprio(1);
#pragma unroll
    for (int m = 0; m < 4; ++m) {
      acc[m][2] = MFMA16(af[1][m], bfr[1][2], acc[m][2]);
      acc[m][3] = MFMA16(af[1][m], bfr[1][3], acc[m][3]);
    }
    __builtin_amdgcn_s_setprio(0);
  }
#undef QKV_STAGE_ALL
  const int e0 = n0 + wc * 64;
  const int which = e0 >> 10;
  const int h = (e0 >> 6) & 15;
  if (which == 2) {
#pragma unroll
    for (int m = 0; m < 4; ++m) {
      int mg = m0 + wr * 64 + m * 16 + g * 4;
      int b = mg >> 11, s = mg & 2047;
#pragma unroll
      for (int n = 0; n < 4; ++n) {
        int d = n * 16 + col;
        alignas(8) bf16 t[4];
#pragma unroll
        for (int r = 0; r < 4; ++r) t[r] = __float2bfloat16(acc[m][n][r]);
        *reinterpret_cast<uint2*>(&Vtw[((size_t)((b * 16 + h) * 64 + d) << 11) + s]) =
            *reinterpret_cast<uint2*>(t);
      }
    }
  } else {
    bf16* dst = which ? Kw : Qw;
    const float scale = which ? 1.0f : 0.18033688011112042f;  // 0.125*log2(e)
    const float fexp = -2.0f * 13.287712379549449f / 64.0f;
#pragma unroll
    for (int i = 0; i < 2; ++i) {
      int dlo = i * 16 + col;
      float invf = exp2f(fexp * (float)dlo);
#pragma unroll
      for (int m = 0; m < 4; ++m) {
        int mg = m0 + wr * 64 + m * 16 + g * 4;
        int b = mg >> 11;
        size_t rb = (size_t)(b * 16 + h) << 11;
#pragma unroll
        for (int r = 0; r < 4; ++r) {
          int s = (mg + r) & 2047;
          float sn, cs;
          __sincosf((float)s * invf, &sn, &cs);
          float lo = acc[m][i][r] * scale, hi = acc[m][i + 2][r] * scale;
          dst[((rb + s) << 6) + dlo] = __float2bfloat16(lo * cs - hi * sn);
          dst[((rb + s) << 6) + dlo + 32] = __float2bfloat16(hi * cs + lo * sn);
        }
      }
    }
  }
}

// ---------------------------------------------------------------- flash attention
// R13 LDS structure (R14 proved staging is load-bearing) + XOR-swizzled
// stride-64 LDS everywhere (R10-pattern, measured 0 conflicts in GEMM):
// row stride 64 (no pad), element offset ^= (row&7)*8 on BOTH write and
// read for Q, K, V, P. LDS 32KB -> 4 blocks/CU.
__global__ __launch_bounds__(512) void k_attn(const bf16* __restrict__ Q,
                                              const bf16* __restrict__ K,
                                              const bf16* __restrict__ Vt,
                                              bf16* __restrict__ AO) {
  __shared__ bf16 QPl[128][64];  // Q staging, then P buffer (wave-private rows)
  __shared__ bf16 Kl[64][64];
  __shared__ bf16 Vl[64][64];  // [d][key]
  const int tid = threadIdx.x;
  const int wave = tid >> 6, lane = tid & 63, col = lane & 15, g = lane >> 4;
  const int bh = blockIdx.x;
  const size_t base = (size_t)bh << 17;
  const int r0 = tid >> 3, c0 = (tid & 7) * 8;  // r0: 0..63
  const int c0s = c0 ^ ((r0 & 7) * 8);          // swizzled write col
  const int swc = (col & 7) * 8;                // swizzled read XOR (row = *+col)
  const int b = bh >> 4, h = bh & 15;
  // y -> qt mapping: quartets {y,y+4,y+8,y+12} sum to 30 => equal per-CU work
  const int yy = blockIdx.y, a = yy >> 2, r_ = yy & 3;
  const int qt = (a == 0) ? (15 - r_) : (a == 1) ? (8 + (r_ ^ 2)) : (a == 2) ? (4 + (r_ ^ 1)) : r_;
  const int q0 = qt * 128;
  // stage Q tile (swizzled)
  *reinterpret_cast<int4*>(&QPl[r0][c0s]) =
      *reinterpret_cast<const int4*>(&Q[base + (size_t)(q0 + r0) * 64 + c0]);
  *reinterpret_cast<int4*>(&QPl[r0 + 64][c0s]) =
      *reinterpret_cast<const int4*>(&Q[base + (size_t)(q0 + r0 + 64) * 64 + c0]);
  const int ktlim = 2 * qt + 1;                  // block-wide last tile (incl.)
  const int ktmax = (q0 + wave * 16 + 15) >> 6;  // this wave's last useful tile
  // tile 0 -> LDS; tile 1 -> regs
  int4 kr = *reinterpret_cast<const int4*>(&K[base + (size_t)r0 * 64 + c0]);
  int4 vr = *reinterpret_cast<const int4*>(&Vt[base + (size_t)r0 * 2048 + c0]);
  *reinterpret_cast<int4*>(&Kl[r0][c0s]) = kr;
  *reinterpret_cast<int4*>(&Vl[r0][c0s]) = vr;
  kr = *reinterpret_cast<const int4*>(&K[base + (size_t)(64 + r0) * 64 + c0]);
  vr = *reinterpret_cast<const int4*>(&Vt[base + (size_t)r0 * 2048 + 64 + c0]);
  __syncthreads();
  bf16x8 qf[2];
#pragma unroll
  for (int kk = 0; kk < 2; ++kk)
    qf[kk] = *reinterpret_cast<const bf16x8*>(
        &QPl[wave * 16 + col][(g * 8 + kk * 32) ^ swc]);
  float l_s = 0.0f;
  f32x4 o[4] = {};
  for (int kt = 0; kt <= ktlim; ++kt) {
    const int k0 = kt * 64;
    if (kt <= ktmax) {
      const int q = q0 + wave * 16 + col;
      const bool needmask = (k0 + 63 > q0 + wave * 16);  // wave-uniform
      __builtin_amdgcn_s_setprio(1);
#pragma unroll
      for (int n = 0; n < 4; ++n) {
        f32x4 s = {};
#pragma unroll
        for (int kk = 0; kk < 2; ++kk) {
          bf16x8 kf = *reinterpret_cast<const bf16x8*>(
              &Kl[n * 16 + col][(g * 8 + kk * 32) ^ swc]);
          s = MFMA16(kf, qf[kk], s);
        }
        if (needmask) {
#pragma unroll
          for (int r = 0; r < 4; ++r)
            if (k0 + n * 16 + g * 4 + r > q) s[r] = -3e38f;
        }
        alignas(8) bf16 t[4];
#pragma unroll
        for (int r = 0; r < 4; ++r) {
          float p = exp2f(s[r]);
          l_s += p;
          t[r] = __float2bfloat16(p);
        }
        *reinterpret_cast<uint2*>(&QPl[wave * 16 + col][(n * 16 + g * 4) ^ swc]) =
            *reinterpret_cast<uint2*>(t);
      }
      // O += P V   (P in wave-private LDS rows, swizzled)
#pragma unroll
      for (int kk = 0; kk < 2; ++kk) {
        bf16x8 pf = *reinterpret_cast<const bf16x8*>(
            &QPl[wave * 16 + col][(g * 8 + kk * 32) ^ swc]);
#pragma unroll
        for (int n2 = 0; n2 < 4; ++n2) {
          bf16x8 vf = *reinterpret_cast<const bf16x8*>(
              &Vl[n2 * 16 + col][(g * 8 + kk * 32) ^ swc]);
          o[n2] = MFMA16(pf, vf, o[n2]);
        }
      }
      __builtin_amdgcn_s_setprio(0);
    }
    __syncthreads();  // all waves done reading Kl/Vl
    if (kt < ktlim) {
      *reinterpret_cast<int4*>(&Kl[r0][c0s]) = kr;
      *reinterpret_cast<int4*>(&Vl[r0][c0s]) = vr;
      if (kt + 2 <= ktlim) {
        const int k2 = k0 + 128;
        kr = *reinterpret_cast<const int4*>(&K[base + (size_t)(k2 + r0) * 64 + c0]);
        vr = *reinterpret_cast<const int4*>(&Vt[base + (size_t)r0 * 2048 + k2 + c0]);
      }
      __syncthreads();  // staged tile visible
    }
  }
  l_s += __shfl_xor(l_s, 16);
  l_s += __shfl_xor(l_s, 32);
#pragma unroll
  for (int r = 0; r < 4; ++r) {
    float inv = 1.0f / __shfl(l_s, (lane & 48) | (g * 4 + r));
    int s = q0 + wave * 16 + g * 4 + r;
#pragma unroll
    for (int n2 = 0; n2 < 4; ++n2)
      AO[((size_t)(b * 2048 + s) << 10) + h * 64 + n2 * 16 + col] =
          __float2bfloat16(o[n2][r] * inv);
  }
}

// ---------------------------------------------------------------- out projection (R13: interleaved counted-vmcnt)
__global__ __launch_bounds__(512) void k_outproj(const bf16* __restrict__ A,
                                                 const bf16* __restrict__ W,
                                                 float* __restrict__ OUT) {
  __shared__ bf16 Al[2][128 * 64];
  __shared__ bf16 Bl[2][256 * 64];
  const int tid = threadIdx.x;
  const int wid = tid >> 6, lane = tid & 63, col = lane & 15, g = lane >> 4;
  const int wr = wid >> 2, wc = wid & 3;
  const int m0 = blockIdx.x * 128, n0 = blockIdx.y * 256;
  const int srow = tid >> 3;
  const int scol = (tid & 7) * 8;
  const int csrc = scol ^ ((srow & 7) * 8);
  const bf16* ga = A + (size_t)(m0 + srow) * 1024 + csrc;
  const bf16* gb = W + (size_t)(n0 + srow) * 1024 + csrc;
  const int ldst = srow * 64 + scol;
  const int rsw = (col & 7) * 8;
  f32x4 acc[4][4] = {};
#define OP_STAGE_ALL(buf, k0)                                \
  do {                                                       \
    gload16(ga + (k0), &Al[buf][ldst]);                      \
    gload16(ga + (k0) + 64 * 1024, &Al[buf][ldst + 4096]);   \
    gload16(gb + (k0), &Bl[buf][ldst]);                      \
    gload16(gb + (k0) + 64 * 1024, &Bl[buf][ldst + 4096]);   \
    gload16(gb + (k0) + 128 * 1024, &Bl[buf][ldst + 8192]);  \
    gload16(gb + (k0) + 192 * 1024, &Bl[buf][ldst + 12288]); \
  } while (0)
  OP_STAGE_ALL(0, 0);
  OP_STAGE_ALL(1, 64);
  for (int kt = 0; kt < 16; ++kt) {
    const int c = kt & 1;
    if (kt < 15)
      asm volatile("s_waitcnt vmcnt(6)" ::: "memory");
    else
      asm volatile("s_waitcnt vmcnt(0)" ::: "memory");
    __builtin_amdgcn_s_barrier();
    const bf16* Ac = Al[c];
    const bf16* Bc = Bl[c];
    bf16x8 af[2][4], bfr[2][4];
#pragma unroll
    for (int kk = 0; kk < 2; ++kk) {
      const int ce = (kk * 32 + g * 8) ^ rsw;
#pragma unroll
      for (int m = 0; m < 4; ++m)
        af[kk][m] =
            *reinterpret_cast<const bf16x8*>(&Ac[(wr * 64 + m * 16 + col) * 64 + ce]);
#pragma unroll
      for (int n = 0; n < 4; ++n)
        bfr[kk][n] =
            *reinterpret_cast<const bf16x8*>(&Bc[(wc * 64 + n * 16 + col) * 64 + ce]);
    }
    __builtin_amdgcn_s_setprio(1);
#pragma unroll
    for (int m = 0; m < 4; ++m) {
      acc[m][0] = MFMA16(af[0][m], bfr[0][0], acc[m][0]);
      acc[m][1] = MFMA16(af[0][m], bfr[0][1], acc[m][1]);
    }
    __builtin_amdgcn_s_setprio(0);
    asm volatile("s_waitcnt lgkmcnt(0)" ::: "memory");
    __builtin_amdgcn_sched_barrier(0);
    __builtin_amdgcn_s_barrier();
    const bool more = (kt + 2 < 16);
    const int k2 = (kt + 2) * 64;
    if (more) {
      gload16(ga + k2, &Al[c][ldst]);
      gload16(ga + k2 + 64 * 1024, &Al[c][ldst + 4096]);
    }
    __builtin_amdgcn_s_setprio(1);
#pragma unroll
    for (int m = 0; m < 4; ++m) {
      acc[m][2] = MFMA16(af[0][m], bfr[0][2], acc[m][2]);
      acc[m][3] = MFMA16(af[0][m], bfr[0][3], acc[m][3]);
    }
    __builtin_amdgcn_s_setprio(0);
    if (more) {
      gload16(gb + k2, &Bl[c][ldst]);
      gload16(gb + k2 + 64 * 1024, &Bl[c][ldst + 4096]);
    }
    __builtin_amdgcn_s_setprio(1);
#pragma unroll
    for (int m = 0; m < 4; ++m) {
      acc[m][0] = MFMA16(af[1][m], bfr[1][0], acc[m][0]);
      acc[m][1] = MFMA16(af[1][m], bfr[1][1], acc[m][1]);
    }
    __builtin_amdgcn_s_setprio(0);
    if (more) {
      gload16(gb + k2 + 128 * 1024, &Bl[c][ldst + 8192]);
      gload16(gb + k2 + 192 * 1024, &Bl[c][ldst + 12288]);
    }
    __builtin_amdgcn_s_setprio(1);
#pragma unroll
    for (int m = 0; m < 4; ++m) {
      acc[m][2] = MFMA16(af[1][m], bfr[1][2], acc[m][2]);
      acc[m][3] = MFMA16(af[1][m], bfr[1][3], acc[m][3]);
    }
    __builtin_amdgcn_s_setprio(0);
  }
#undef OP_STAGE_ALL
#pragma unroll
  for (int m = 0; m < 4; ++m)
#pragma unroll
    for (int n = 0; n < 4; ++n)
#pragma unroll
      for (int r = 0; r < 4; ++r)
        OUT[(size_t)(m0 + wr * 64 + m * 16 + g * 4 + r) * 1024 + n0 + wc * 64 + n * 16 +
            col] = acc[m][n][r];
}

// ---------------------------------------------------------------- launcher
extern "C" void kernel_launch(void* const* d_in, const int* in_sizes, int n_in,
                              void* d_out, int out_size, void* d_ws, size_t ws_size,
                              hipStream_t stream) {
  const float* x = (const float*)d_in[0];
  const float* wqkv = (const float*)d_in[1];
  const float* wout = (const float*)d_in[2];
  float* out = (float*)d_out;

  char* ws = (char*)d_ws;
  const size_t SZ_X = (size_t)B_ * S_ * D_ * 2;
  const size_t SZ_WQKV = (size_t)3 * D_ * D_ * 2;
  const size_t SZ_WOUT = (size_t)D_ * D_ * 2;
  const size_t SZ_T = (size_t)B_ * H_ * S_ * HD_ * 2;
  bf16* xb = (bf16*)(ws);
  bf16* wqkvb = (bf16*)(ws + SZ_X);
  bf16* woutb = (bf16*)(ws + SZ_X + SZ_WQKV);
  bf16* qws = (bf16*)(ws + SZ_X + SZ_WQKV + SZ_WOUT);
  bf16* kws = (bf16*)(ws + SZ_X + SZ_WQKV + SZ_WOUT + SZ_T);
  bf16* vtws = (bf16*)(ws + SZ_X + SZ_WQKV + SZ_WOUT + 2 * SZ_T);
  bf16* aob = (bf16*)(ws + SZ_X + SZ_WQKV + SZ_WOUT + 3 * SZ_T);

  const int NTOT4 = (NX_ + NW1_ + NW2_) / 4;
  k_cvt3<<<NTOT4 / 256, 256, 0, stream>>>(x, wqkv, wout, xb, wqkvb, woutb);

  k_qkv<<<dim3(64, 12), 512, 0, stream>>>(xb, wqkvb, qws, kws, vtws);
  k_attn<<<dim3(B_ * H_, 16), 512, 0, stream>>>(qws, kws, vtws, aob);
  k_outproj<<<dim3(64, 4), 512, 0, stream>>>(aob, woutb, out);
}

// Round 16
// 159.269 us; speedup vs baseline: 2.2294x; 1.0165x over previous
//
#include <hip/hip_runtime.h>
#include <hip/hip_bf16.h>

typedef __bf16 bf16x8 __attribute__((ext_vector_type(8)));
typedef float f32x4 __attribute__((ext_vector_type(4)));
typedef __hip_bfloat16 bf16;

#define B_ 4
#define S_ 2048
#define D_ 1024
#define H_ 16
#define HD_ 64

__device__ __forceinline__ void gload16(const bf16* g, bf16* l) {
  __builtin_amdgcn_global_load_lds(
      (const __attribute__((address_space(1))) unsigned int*)g,
      (__attribute__((address_space(3))) unsigned int*)l, 16, 0, 0);
}

#define MFMA16(a, b, c) __builtin_amdgcn_mfma_f32_16x16x32_bf16((a), (b), (c), 0, 0, 0)

// ---------------------------------------------------------------- cvt f32->bf16 (fused x, w_qkv, w_out)
#define NX_ (B_ * S_ * D_)
#define NW1_ (3 * D_ * D_)
#define NW2_ (D_ * D_)
__global__ __launch_bounds__(256) void k_cvt3(const float* __restrict__ x,
                                              const float* __restrict__ w1,
                                              const float* __restrict__ w2,
                                              bf16* __restrict__ ox,
                                              bf16* __restrict__ o1,
                                              bf16* __restrict__ o2) {
  int i = (blockIdx.x * 256 + threadIdx.x) * 4;
  const float* in;
  bf16* out;
  if (i < NX_) {
    in = x; out = ox;
  } else if (i < NX_ + NW1_) {
    in = w1; out = o1; i -= NX_;
  } else {
    in = w2; out = o2; i -= NX_ + NW1_;
  }
  float4 v = *reinterpret_cast<const float4*>(in + i);
  alignas(8) bf16 t[4];
  t[0] = __float2bfloat16(v.x);
  t[1] = __float2bfloat16(v.y);
  t[2] = __float2bfloat16(v.z);
  t[3] = __float2bfloat16(v.w);
  *reinterpret_cast<uint2*>(out + i) = *reinterpret_cast<uint2*>(t);
}

// ---------------------------------------------------------------- QKV GEMM (R13: interleaved counted-vmcnt)
__global__ __launch_bounds__(512) void k_qkv(const bf16* __restrict__ X,
                                             const bf16* __restrict__ W,
                                             bf16* __restrict__ Qw,
                                             bf16* __restrict__ Kw,
                                             bf16* __restrict__ Vtw) {
  __shared__ bf16 Al[2][128 * 64];  // 32 KB
  __shared__ bf16 Bl[2][256 * 64];  // 64 KB
  const int tid = threadIdx.x;
  const int wid = tid >> 6, lane = tid & 63, col = lane & 15, g = lane >> 4;
  const int wr = wid >> 2, wc = wid & 3;
  const int m0 = blockIdx.x * 128, n0 = blockIdx.y * 256;
  const int srow = tid >> 3;                 // 0..63
  const int scol = (tid & 7) * 8;
  const int csrc = scol ^ ((srow & 7) * 8);  // pre-swizzled source col
  const bf16* ga = X + (size_t)(m0 + srow) * 1024 + csrc;
  const bf16* gb = W + (size_t)(n0 + srow) * 1024 + csrc;
  const int ldst = srow * 64 + scol;         // linear LDS dest
  const int rsw = (col & 7) * 8;
  f32x4 acc[4][4] = {};
#define QKV_STAGE_ALL(buf, k0)                               \
  do {                                                       \
    gload16(ga + (k0), &Al[buf][ldst]);                      \
    gload16(ga + (k0) + 64 * 1024, &Al[buf][ldst + 4096]);   \
    gload16(gb + (k0), &Bl[buf][ldst]);                      \
    gload16(gb + (k0) + 64 * 1024, &Bl[buf][ldst + 4096]);   \
    gload16(gb + (k0) + 128 * 1024, &Bl[buf][ldst + 8192]);  \
    gload16(gb + (k0) + 192 * 1024, &Bl[buf][ldst + 12288]); \
  } while (0)
  QKV_STAGE_ALL(0, 0);
  QKV_STAGE_ALL(1, 64);
  for (int kt = 0; kt < 16; ++kt) {
    const int c = kt & 1;
    if (kt < 15)
      asm volatile("s_waitcnt vmcnt(6)" ::: "memory");
    else
      asm volatile("s_waitcnt vmcnt(0)" ::: "memory");
    __builtin_amdgcn_s_barrier();  // tile kt landed for all waves
    const bf16* Ac = Al[c];
    const bf16* Bc = Bl[c];
    bf16x8 af[2][4], bfr[2][4];
#pragma unroll
    for (int kk = 0; kk < 2; ++kk) {
      const int ce = (kk * 32 + g * 8) ^ rsw;
#pragma unroll
      for (int m = 0; m < 4; ++m)
        af[kk][m] =
            *reinterpret_cast<const bf16x8*>(&Ac[(wr * 64 + m * 16 + col) * 64 + ce]);
#pragma unroll
      for (int n = 0; n < 4; ++n)
        bfr[kk][n] =
            *reinterpret_cast<const bf16x8*>(&Bc[(wc * 64 + n * 16 + col) * 64 + ce]);
    }
    __builtin_amdgcn_s_setprio(1);
#pragma unroll
    for (int m = 0; m < 4; ++m) {
      acc[m][0] = MFMA16(af[0][m], bfr[0][0], acc[m][0]);
      acc[m][1] = MFMA16(af[0][m], bfr[0][1], acc[m][1]);
    }
    __builtin_amdgcn_s_setprio(0);
    asm volatile("s_waitcnt lgkmcnt(0)" ::: "memory");
    __builtin_amdgcn_sched_barrier(0);
    __builtin_amdgcn_s_barrier();  // all waves' reads of buf c complete -> free
    const bool more = (kt + 2 < 16);
    const int k2 = (kt + 2) * 64;
    if (more) {
      gload16(ga + k2, &Al[c][ldst]);
      gload16(ga + k2 + 64 * 1024, &Al[c][ldst + 4096]);
    }
    __builtin_amdgcn_s_setprio(1);
#pragma unroll
    for (int m = 0; m < 4; ++m) {
      acc[m][2] = MFMA16(af[0][m], bfr[0][2], acc[m][2]);
      acc[m][3] = MFMA16(af[0][m], bfr[0][3], acc[m][3]);
    }
    __builtin_amdgcn_s_setprio(0);
    if (more) {
      gload16(gb + k2, &Bl[c][ldst]);
      gload16(gb + k2 + 64 * 1024, &Bl[c][ldst + 4096]);
    }
    __builtin_amdgcn_s_setprio(1);
#pragma unroll
    for (int m = 0; m < 4; ++m) {
      acc[m][0] = MFMA16(af[1][m], bfr[1][0], acc[m][0]);
      acc[m][1] = MFMA16(af[1][m], bfr[1][1], acc[m][1]);
    }
    __builtin_amdgcn_s_setprio(0);
    if (more) {
      gload16(gb + k2 + 128 * 1024, &Bl[c][ldst + 8192]);
      gload16(gb + k2 + 192 * 1024, &Bl[c][ldst + 12288]);
    }
    __builtin_amdgcn_s_setprio(1);
#pragma unroll
    for (int m = 0; m < 4; ++m) {
      acc[m][2] = MFMA16(af[1][m], bfr[1][2], acc[m][2]);
      acc[m][3] = MFMA16(af[1][m], bfr[1][3], acc[m][3]);
    }
    __builtin_amdgcn_s_setprio(0);
  }
#undef QKV_STAGE_ALL
  const int e0 = n0 + wc * 64;
  const int which = e0 >> 10;
  const int h = (e0 >> 6) & 15;
  if (which == 2) {
#pragma unroll
    for (int m = 0; m < 4; ++m) {
      int mg = m0 + wr * 64 + m * 16 + g * 4;
      int b = mg >> 11, s = mg & 2047;
#pragma unroll
      for (int n = 0; n < 4; ++n) {
        int d = n * 16 + col;
        alignas(8) bf16 t[4];
#pragma unroll
        for (int r = 0; r < 4; ++r) t[r] = __float2bfloat16(acc[m][n][r]);
        *reinterpret_cast<uint2*>(&Vtw[((size_t)((b * 16 + h) * 64 + d) << 11) + s]) =
            *reinterpret_cast<uint2*>(t);
      }
    }
  } else {
    bf16* dst = which ? Kw : Qw;
    const float scale = which ? 1.0f : 0.18033688011112042f;  // 0.125*log2(e)
    const float fexp = -2.0f * 13.287712379549449f / 64.0f;
#pragma unroll
    for (int i = 0; i < 2; ++i) {
      int dlo = i * 16 + col;
      float invf = exp2f(fexp * (float)dlo);
#pragma unroll
      for (int m = 0; m < 4; ++m) {
        int mg = m0 + wr * 64 + m * 16 + g * 4;
        int b = mg >> 11;
        size_t rb = (size_t)(b * 16 + h) << 11;
#pragma unroll
        for (int r = 0; r < 4; ++r) {
          int s = (mg + r) & 2047;
          float sn, cs;
          __sincosf((float)s * invf, &sn, &cs);
          float lo = acc[m][i][r] * scale, hi = acc[m][i + 2][r] * scale;
          dst[((rb + s) << 6) + dlo] = __float2bfloat16(lo * cs - hi * sn);
          dst[((rb + s) << 6) + dlo + 32] = __float2bfloat16(hi * cs + lo * sn);
        }
      }
    }
  }
}

// ---------------------------------------------------------------- flash attention
// R13 compute structure; staging ported to the proven GEMM pattern:
// global_load_lds -> double-buffered K/V (linear stride 64, both-sides XOR
// swizzle), counted vmcnt(2) at tile top (next tile's loads stay in flight
// across barriers), raw s_barrier, stage kt+2 after the consume barrier.
// Q fragments read directly from global (one-time). P keeps R13 pad-72
// layout. LDS 50KB -> 3 blocks/CU.
__global__ __launch_bounds__(512) void k_attn(const bf16* __restrict__ Q,
                                              const bf16* __restrict__ K,
                                              const bf16* __restrict__ Vt,
                                              bf16* __restrict__ AO) {
  __shared__ bf16 Pl[128][72];     // per-wave P rows (pad-72, R13 layout)
  __shared__ bf16 Kl[2][64 * 64];  // [key][d], linear, swizzled content
  __shared__ bf16 Vl[2][64 * 64];  // [d][key], linear, swizzled content
  const int tid = threadIdx.x;
  const int wave = tid >> 6, lane = tid & 63, col = lane & 15, g = lane >> 4;
  const int bh = blockIdx.x;
  const size_t base = (size_t)bh << 17;
  const int r0 = tid >> 3, c0 = (tid & 7) * 8;   // r0: 0..63
  const int c0s = c0 ^ ((r0 & 7) * 8);           // pre-swizzled SOURCE col
  const int ldst = r0 * 64 + c0;                 // linear LDS dest (= tid*8)
  const int swc = (col & 7) * 8;                 // read-side XOR (row&7 == col&7)
  const int b = bh >> 4, h = bh & 15;
  // y -> qt mapping: quartets {y,y+4,y+8,y+12} sum to 30 (LPT-ordered too)
  const int yy = blockIdx.y, a = yy >> 2, r_ = yy & 3;
  const int qt = (a == 0) ? (15 - r_) : (a == 1) ? (8 + (r_ ^ 2)) : (a == 2) ? (4 + (r_ ^ 1)) : r_;
  const int q0 = qt * 128;
  const int qw = q0 + wave * 16;
  const int q = qw + col;
  // Q fragments straight from global (one-time)
  const bf16* Qp = Q + base + (size_t)q * 64 + g * 8;
  bf16x8 qf[2];
  qf[0] = *reinterpret_cast<const bf16x8*>(Qp);
  qf[1] = *reinterpret_cast<const bf16x8*>(Qp + 32);
  const int ktlim = 2 * qt + 1;      // block-wide last tile (incl.)
  const int ktmax = (qw + 15) >> 6;  // this wave's last useful tile
  const bf16* Ks = K + base + c0s;
  const bf16* Vs = Vt + base + (size_t)r0 * 2048 + c0s;
#define ATT_STAGE(buf, k0)                                  \
  do {                                                      \
    gload16(Ks + (size_t)((k0) + r0) * 64, &Kl[buf][ldst]); \
    gload16(Vs + (k0), &Vl[buf][ldst]);                     \
  } while (0)
  // prologue: tiles 0 and 1
  ATT_STAGE(0, 0);
  ATT_STAGE(1, 64);
  float l_s = 0.0f;
  f32x4 o[4] = {};
  for (int kt = 0; kt <= ktlim; ++kt) {
    const int c = kt & 1;
    const int k0 = kt * 64;
    if (kt < ktlim)
      asm volatile("s_waitcnt vmcnt(2)" ::: "memory");
    else
      asm volatile("s_waitcnt vmcnt(0)" ::: "memory");
    __builtin_amdgcn_s_barrier();  // tile kt landed for all waves
    if (kt <= ktmax) {
      const bool needmask = (k0 + 63 > qw);  // wave-uniform
      __builtin_amdgcn_s_setprio(1);
#pragma unroll
      for (int n = 0; n < 4; ++n) {
        f32x4 s = {};
#pragma unroll
        for (int kk = 0; kk < 2; ++kk) {
          bf16x8 kf = *reinterpret_cast<const bf16x8*>(
              &Kl[c][(n * 16 + col) * 64 + ((g * 8 + kk * 32) ^ swc)]);
          s = MFMA16(kf, qf[kk], s);
        }
        if (needmask) {
#pragma unroll
          for (int r = 0; r < 4; ++r)
            if (k0 + n * 16 + g * 4 + r > q) s[r] = -3e38f;
        }
        alignas(8) bf16 t[4];
#pragma unroll
        for (int r = 0; r < 4; ++r) {
          float p = exp2f(s[r]);
          l_s += p;
          t[r] = __float2bfloat16(p);
        }
        *reinterpret_cast<uint2*>(&Pl[wave * 16 + col][n * 16 + g * 4]) =
            *reinterpret_cast<uint2*>(t);
      }
      // O += P V   (P wave-private)
#pragma unroll
      for (int kk = 0; kk < 2; ++kk) {
        bf16x8 pf =
            *reinterpret_cast<const bf16x8*>(&Pl[wave * 16 + col][g * 8 + kk * 32]);
#pragma unroll
        for (int n2 = 0; n2 < 4; ++n2) {
          bf16x8 vf = *reinterpret_cast<const bf16x8*>(
              &Vl[c][(n2 * 16 + col) * 64 + ((g * 8 + kk * 32) ^ swc)]);
          o[n2] = MFMA16(pf, vf, o[n2]);
        }
      }
      __builtin_amdgcn_s_setprio(0);
    }
    __builtin_amdgcn_s_barrier();  // all waves done reading buf c
    if (kt + 2 <= ktlim) ATT_STAGE(c, k0 + 128);
  }
#undef ATT_STAGE
  l_s += __shfl_xor(l_s, 16);
  l_s += __shfl_xor(l_s, 32);
#pragma unroll
  for (int r = 0; r < 4; ++r) {
    float inv = 1.0f / __shfl(l_s, (lane & 48) | (g * 4 + r));
    int s = qw + g * 4 + r;
#pragma unroll
    for (int n2 = 0; n2 < 4; ++n2)
      AO[((size_t)(b * 2048 + s) << 10) + h * 64 + n2 * 16 + col] =
          __float2bfloat16(o[n2][r] * inv);
  }
}

// ---------------------------------------------------------------- out projection (R13: interleaved counted-vmcnt)
__global__ __launch_bounds__(512) void k_outproj(const bf16* __restrict__ A,
                                                 const bf16* __restrict__ W,
                                                 float* __restrict__ OUT) {
  __shared__ bf16 Al[2][128 * 64];
  __shared__ bf16 Bl[2][256 * 64];
  const int tid = threadIdx.x;
  const int wid = tid >> 6, lane = tid & 63, col = lane & 15, g = lane >> 4;
  const int wr = wid >> 2, wc = wid & 3;
  const int m0 = blockIdx.x * 128, n0 = blockIdx.y * 256;
  const int srow = tid >> 3;
  const int scol = (tid & 7) * 8;
  const int csrc = scol ^ ((srow & 7) * 8);
  const bf16* ga = A + (size_t)(m0 + srow) * 1024 + csrc;
  const bf16* gb = W + (size_t)(n0 + srow) * 1024 + csrc;
  const int ldst = srow * 64 + scol;
  const int rsw = (col & 7) * 8;
  f32x4 acc[4][4] = {};
#define OP_STAGE_ALL(buf, k0)                                \
  do {                                                       \
    gload16(ga + (k0), &Al[buf][ldst]);                      \
    gload16(ga + (k0) + 64 * 1024, &Al[buf][ldst + 4096]);   \
    gload16(gb + (k0), &Bl[buf][ldst]);                      \
    gload16(gb + (k0) + 64 * 1024, &Bl[buf][ldst + 4096]);   \
    gload16(gb + (k0) + 128 * 1024, &Bl[buf][ldst + 8192]);  \
    gload16(gb + (k0) + 192 * 1024, &Bl[buf][ldst + 12288]); \
  } while (0)
  OP_STAGE_ALL(0, 0);
  OP_STAGE_ALL(1, 64);
  for (int kt = 0; kt < 16; ++kt) {
    const int c = kt & 1;
    if (kt < 15)
      asm volatile("s_waitcnt vmcnt(6)" ::: "memory");
    else
      asm volatile("s_waitcnt vmcnt(0)" ::: "memory");
    __builtin_amdgcn_s_barrier();
    const bf16* Ac = Al[c];
    const bf16* Bc = Bl[c];
    bf16x8 af[2][4], bfr[2][4];
#pragma unroll
    for (int kk = 0; kk < 2; ++kk) {
      const int ce = (kk * 32 + g * 8) ^ rsw;
#pragma unroll
      for (int m = 0; m < 4; ++m)
        af[kk][m] =
            *reinterpret_cast<const bf16x8*>(&Ac[(wr * 64 + m * 16 + col) * 64 + ce]);
#pragma unroll
      for (int n = 0; n < 4; ++n)
        bfr[kk][n] =
            *reinterpret_cast<const bf16x8*>(&Bc[(wc * 64 + n * 16 + col) * 64 + ce]);
    }
    __builtin_amdgcn_s_setprio(1);
#pragma unroll
    for (int m = 0; m < 4; ++m) {
      acc[m][0] = MFMA16(af[0][m], bfr[0][0], acc[m][0]);
      acc[m][1] = MFMA16(af[0][m], bfr[0][1], acc[m][1]);
    }
    __builtin_amdgcn_s_setprio(0);
    asm volatile("s_waitcnt lgkmcnt(0)" ::: "memory");
    __builtin_amdgcn_sched_barrier(0);
    __builtin_amdgcn_s_barrier();
    const bool more = (kt + 2 < 16);
    const int k2 = (kt + 2) * 64;
    if (more) {
      gload16(ga + k2, &Al[c][ldst]);
      gload16(ga + k2 + 64 * 1024, &Al[c][ldst + 4096]);
    }
    __builtin_amdgcn_s_setprio(1);
#pragma unroll
    for (int m = 0; m < 4; ++m) {
      acc[m][2] = MFMA16(af[0][m], bfr[0][2], acc[m][2]);
      acc[m][3] = MFMA16(af[0][m], bfr[0][3], acc[m][3]);
    }
    __builtin_amdgcn_s_setprio(0);
    if (more) {
      gload16(gb + k2, &Bl[c][ldst]);
      gload16(gb + k2 + 64 * 1024, &Bl[c][ldst + 4096]);
    }
    __builtin_amdgcn_s_setprio(1);
#pragma unroll
    for (int m = 0; m < 4; ++m) {
      acc[m][0] = MFMA16(af[1][m], bfr[1][0], acc[m][0]);
      acc[m][1] = MFMA16(af[1][m], bfr[1][1], acc[m][1]);
    }
    __builtin_amdgcn_s_setprio(0);
    if (more) {
      gload16(gb + k2 + 128 * 1024, &Bl[c][ldst + 8192]);
      gload16(gb + k2 + 192 * 1024, &Bl[c][ldst + 12288]);
    }
    __builtin_amdgcn_s_setprio(1);
#pragma unroll
    for (int m = 0; m < 4; ++m) {
      acc[m][2] = MFMA16(af[1][m], bfr[1][2], acc[m][2]);
      acc[m][3] = MFMA16(af[1][m], bfr[1][3], acc[m][3]);
    }
    __builtin_amdgcn_s_setprio(0);
  }
#undef OP_STAGE_ALL
#pragma unroll
  for (int m = 0; m < 4; ++m)
#pragma unroll
    for (int n = 0; n < 4; ++n)
#pragma unroll
      for (int r = 0; r < 4; ++r)
        OUT[(size_t)(m0 + wr * 64 + m * 16 + g * 4 + r) * 1024 + n0 + wc * 64 + n * 16 +
            col] = acc[m][n][r];
}

// ---------------------------------------------------------------- launcher
extern "C" void kernel_launch(void* const* d_in, const int* in_sizes, int n_in,
                              void* d_out, int out_size, void* d_ws, size_t ws_size,
                              hipStream_t stream) {
  const float* x = (const float*)d_in[0];
  const float* wqkv = (const float*)d_in[1];
  const float* wout = (const float*)d_in[2];
  float* out = (float*)d_out;

  char* ws = (char*)d_ws;
  const size_t SZ_X = (size_t)B_ * S_ * D_ * 2;
  const size_t SZ_WQKV = (size_t)3 * D_ * D_ * 2;
  const size_t SZ_WOUT = (size_t)D_ * D_ * 2;
  const size_t SZ_T = (size_t)B_ * H_ * S_ * HD_ * 2;
  bf16* xb = (bf16*)(ws);
  bf16* wqkvb = (bf16*)(ws + SZ_X);
  bf16* woutb = (bf16*)(ws + SZ_X + SZ_WQKV);
  bf16* qws = (bf16*)(ws + SZ_X + SZ_WQKV + SZ_WOUT);
  bf16* kws = (bf16*)(ws + SZ_X + SZ_WQKV + SZ_WOUT + SZ_T);
  bf16* vtws = (bf16*)(ws + SZ_X + SZ_WQKV + SZ_WOUT + 2 * SZ_T);
  bf16* aob = (bf16*)(ws + SZ_X + SZ_WQKV + SZ_WOUT + 3 * SZ_T);

  const int NTOT4 = (NX_ + NW1_ + NW2_) / 4;
  k_cvt3<<<NTOT4 / 256, 256, 0, stream>>>(x, wqkv, wout, xb, wqkvb, woutb);

  k_qkv<<<dim3(64, 12), 512, 0, stream>>>(xb, wqkvb, qws, kws, vtws);
  k_attn<<<dim3(B_ * H_, 16), 512, 0, stream>>>(qws, kws, vtws, aob);
  k_outproj<<<dim3(64, 4), 512, 0, stream>>>(aob, woutb, out);
}

// Round 17
// 158.952 us; speedup vs baseline: 2.2338x; 1.0020x over previous
//
#include <hip/hip_runtime.h>
#include <hip/hip_bf16.h>

typedef __bf16 bf16x8 __attribute__((ext_vector_type(8)));
typedef float f32x4 __attribute__((ext_vector_type(4)));
typedef __hip_bfloat16 bf16;

#define B_ 4
#define S_ 2048
#define D_ 1024
#define H_ 16
#define HD_ 64

__device__ __forceinline__ void gload16(const bf16* g, bf16* l) {
  __builtin_amdgcn_global_load_lds(
      (const __attribute__((address_space(1))) unsigned int*)g,
      (__attribute__((address_space(3))) unsigned int*)l, 16, 0, 0);
}

#define MFMA16(a, b, c) __builtin_amdgcn_mfma_f32_16x16x32_bf16((a), (b), (c), 0, 0, 0)

// ---------------------------------------------------------------- cvt f32->bf16 (fused x, w_qkv, w_out)
#define NX_ (B_ * S_ * D_)
#define NW1_ (3 * D_ * D_)
#define NW2_ (D_ * D_)
__global__ __launch_bounds__(256) void k_cvt3(const float* __restrict__ x,
                                              const float* __restrict__ w1,
                                              const float* __restrict__ w2,
                                              bf16* __restrict__ ox,
                                              bf16* __restrict__ o1,
                                              bf16* __restrict__ o2) {
  int i = (blockIdx.x * 256 + threadIdx.x) * 4;
  const float* in;
  bf16* out;
  if (i < NX_) {
    in = x; out = ox;
  } else if (i < NX_ + NW1_) {
    in = w1; out = o1; i -= NX_;
  } else {
    in = w2; out = o2; i -= NX_ + NW1_;
  }
  float4 v = *reinterpret_cast<const float4*>(in + i);
  alignas(8) bf16 t[4];
  t[0] = __float2bfloat16(v.x);
  t[1] = __float2bfloat16(v.y);
  t[2] = __float2bfloat16(v.z);
  t[3] = __float2bfloat16(v.w);
  *reinterpret_cast<uint2*>(out + i) = *reinterpret_cast<uint2*>(t);
}

// ---------------------------------------------------------------- QKV GEMM (R13: interleaved counted-vmcnt)
__global__ __launch_bounds__(512) void k_qkv(const bf16* __restrict__ X,
                                             const bf16* __restrict__ W,
                                             bf16* __restrict__ Qw,
                                             bf16* __restrict__ Kw,
                                             bf16* __restrict__ Vtw) {
  __shared__ bf16 Al[2][128 * 64];  // 32 KB
  __shared__ bf16 Bl[2][256 * 64];  // 64 KB
  const int tid = threadIdx.x;
  const int wid = tid >> 6, lane = tid & 63, col = lane & 15, g = lane >> 4;
  const int wr = wid >> 2, wc = wid & 3;
  const int m0 = blockIdx.x * 128, n0 = blockIdx.y * 256;
  const int srow = tid >> 3;                 // 0..63
  const int scol = (tid & 7) * 8;
  const int csrc = scol ^ ((srow & 7) * 8);  // pre-swizzled source col
  const bf16* ga = X + (size_t)(m0 + srow) * 1024 + csrc;
  const bf16* gb = W + (size_t)(n0 + srow) * 1024 + csrc;
  const int ldst = srow * 64 + scol;         // linear LDS dest
  const int rsw = (col & 7) * 8;
  f32x4 acc[4][4] = {};
#define QKV_STAGE_ALL(buf, k0)                               \
  do {                                                       \
    gload16(ga + (k0), &Al[buf][ldst]);                      \
    gload16(ga + (k0) + 64 * 1024, &Al[buf][ldst + 4096]);   \
    gload16(gb + (k0), &Bl[buf][ldst]);                      \
    gload16(gb + (k0) + 64 * 1024, &Bl[buf][ldst + 4096]);   \
    gload16(gb + (k0) + 128 * 1024, &Bl[buf][ldst + 8192]);  \
    gload16(gb + (k0) + 192 * 1024, &Bl[buf][ldst + 12288]); \
  } while (0)
  QKV_STAGE_ALL(0, 0);
  QKV_STAGE_ALL(1, 64);
  for (int kt = 0; kt < 16; ++kt) {
    const int c = kt & 1;
    if (kt < 15)
      asm volatile("s_waitcnt vmcnt(6)" ::: "memory");
    else
      asm volatile("s_waitcnt vmcnt(0)" ::: "memory");
    __builtin_amdgcn_s_barrier();  // tile kt landed for all waves
    const bf16* Ac = Al[c];
    const bf16* Bc = Bl[c];
    bf16x8 af[2][4], bfr[2][4];
#pragma unroll
    for (int kk = 0; kk < 2; ++kk) {
      const int ce = (kk * 32 + g * 8) ^ rsw;
#pragma unroll
      for (int m = 0; m < 4; ++m)
        af[kk][m] =
            *reinterpret_cast<const bf16x8*>(&Ac[(wr * 64 + m * 16 + col) * 64 + ce]);
#pragma unroll
      for (int n = 0; n < 4; ++n)
        bfr[kk][n] =
            *reinterpret_cast<const bf16x8*>(&Bc[(wc * 64 + n * 16 + col) * 64 + ce]);
    }
    __builtin_amdgcn_s_setprio(1);
#pragma unroll
    for (int m = 0; m < 4; ++m) {
      acc[m][0] = MFMA16(af[0][m], bfr[0][0], acc[m][0]);
      acc[m][1] = MFMA16(af[0][m], bfr[0][1], acc[m][1]);
    }
    __builtin_amdgcn_s_setprio(0);
    asm volatile("s_waitcnt lgkmcnt(0)" ::: "memory");
    __builtin_amdgcn_sched_barrier(0);
    __builtin_amdgcn_s_barrier();  // all waves' reads of buf c complete -> free
    const bool more = (kt + 2 < 16);
    const int k2 = (kt + 2) * 64;
    if (more) {
      gload16(ga + k2, &Al[c][ldst]);
      gload16(ga + k2 + 64 * 1024, &Al[c][ldst + 4096]);
    }
    __builtin_amdgcn_s_setprio(1);
#pragma unroll
    for (int m = 0; m < 4; ++m) {
      acc[m][2] = MFMA16(af[0][m], bfr[0][2], acc[m][2]);
      acc[m][3] = MFMA16(af[0][m], bfr[0][3], acc[m][3]);
    }
    __builtin_amdgcn_s_setprio(0);
    if (more) {
      gload16(gb + k2, &Bl[c][ldst]);
      gload16(gb + k2 + 64 * 1024, &Bl[c][ldst + 4096]);
    }
    __builtin_amdgcn_s_setprio(1);
#pragma unroll
    for (int m = 0; m < 4; ++m) {
      acc[m][0] = MFMA16(af[1][m], bfr[1][0], acc[m][0]);
      acc[m][1] = MFMA16(af[1][m], bfr[1][1], acc[m][1]);
    }
    __builtin_amdgcn_s_setprio(0);
    if (more) {
      gload16(gb + k2 + 128 * 1024, &Bl[c][ldst + 8192]);
      gload16(gb + k2 + 192 * 1024, &Bl[c][ldst + 12288]);
    }
    __builtin_amdgcn_s_setprio(1);
#pragma unroll
    for (int m = 0; m < 4; ++m) {
      acc[m][2] = MFMA16(af[1][m], bfr[1][2], acc[m][2]);
      acc[m][3] = MFMA16(af[1][m], bfr[1][3], acc[m][3]);
    }
    __builtin_amdgcn_s_setprio(0);
  }
#undef QKV_STAGE_ALL
  const int e0 = n0 + wc * 64;
  const int which = e0 >> 10;
  const int h = (e0 >> 6) & 15;
  if (which == 2) {
#pragma unroll
    for (int m = 0; m < 4; ++m) {
      int mg = m0 + wr * 64 + m * 16 + g * 4;
      int b = mg >> 11, s = mg & 2047;
#pragma unroll
      for (int n = 0; n < 4; ++n) {
        int d = n * 16 + col;
        alignas(8) bf16 t[4];
#pragma unroll
        for (int r = 0; r < 4; ++r) t[r] = __float2bfloat16(acc[m][n][r]);
        *reinterpret_cast<uint2*>(&Vtw[((size_t)((b * 16 + h) * 64 + d) << 11) + s]) =
            *reinterpret_cast<uint2*>(t);
      }
    }
  } else {
    bf16* dst = which ? Kw : Qw;
    const float scale = which ? 1.0f : 0.18033688011112042f;  // 0.125*log2(e)
    const float fexp = -2.0f * 13.287712379549449f / 64.0f;
#pragma unroll
    for (int i = 0; i < 2; ++i) {
      int dlo = i * 16 + col;
      float invf = exp2f(fexp * (float)dlo);
#pragma unroll
      for (int m = 0; m < 4; ++m) {
        int mg = m0 + wr * 64 + m * 16 + g * 4;
        int b = mg >> 11;
        size_t rb = (size_t)(b * 16 + h) << 11;
#pragma unroll
        for (int r = 0; r < 4; ++r) {
          int s = (mg + r) & 2047;
          float sn, cs;
          __sincosf((float)s * invf, &sn, &cs);
          float lo = acc[m][i][r] * scale, hi = acc[m][i + 2][r] * scale;
          dst[((rb + s) << 6) + dlo] = __float2bfloat16(lo * cs - hi * sn);
          dst[((rb + s) << 6) + dlo + 32] = __float2bfloat16(hi * cs + lo * sn);
        }
      }
    }
  }
}

// ---------------------------------------------------------------- flash attention
// R16 structure with KVBLK=32: K/V dbuf 16KB + P 18.4KB = 34.8KB LDS ->
// 4 blocks/CU (32 waves, HW cap). Per tile: 4 QK + 4 PV MFMA (PV = single
// K=32 mfma), 1 gload16/thread (tid<256 stages K, >=256 stages V; linear
// dest, pre-swizzled source). vmcnt(1) counted; stage kt+2 after consume
// barrier. l-sum in f32x4 (4 short chains).
__global__ __launch_bounds__(512) void k_attn(const bf16* __restrict__ Q,
                                              const bf16* __restrict__ K,
                                              const bf16* __restrict__ Vt,
                                              bf16* __restrict__ AO) {
  __shared__ bf16 Pl[128][72];     // per-wave P rows (32 cols used)
  __shared__ bf16 Kl[2][32 * 64];  // [key][d], linear, swizzled content
  __shared__ bf16 Vl[2][64 * 32];  // [d][key], linear, swizzled content
  const int tid = threadIdx.x;
  const int wave = tid >> 6, lane = tid & 63, col = lane & 15, g = lane >> 4;
  const int bh = blockIdx.x;
  const size_t base = (size_t)bh << 17;
  const int b = bh >> 4, h = bh & 15;
  const int swc = (col & 7) * 8;   // K read-side XOR
  const int vwc = (col & 3) * 8;   // V read-side XOR (32-wide rows)
  // y -> qt mapping: quartets {y,y+4,y+8,y+12} sum to 30 => equal per-CU work
  const int yy = blockIdx.y, a = yy >> 2, r_ = yy & 3;
  const int qt = (a == 0) ? (15 - r_) : (a == 1) ? (8 + (r_ ^ 2)) : (a == 2) ? (4 + (r_ ^ 1)) : r_;
  const int q0 = qt * 128;
  const int qw = q0 + wave * 16;
  const int q = qw + col;
  // Q fragments straight from global (one-time)
  const bf16* Qp = Q + base + (size_t)q * 64 + g * 8;
  bf16x8 qf[2];
  qf[0] = *reinterpret_cast<const bf16x8*>(Qp);
  qf[1] = *reinterpret_cast<const bf16x8*>(Qp + 32);
  const int ktlim = 4 * qt + 3;      // block-wide last tile (incl.)
  const int ktmax = (qw + 15) >> 5;  // this wave's last useful tile
  // staging split: tid<256 -> K tile (32x64), tid>=256 -> V tile (64x32)
  const bf16* gsrc;
  bf16* ldstp0;
  bf16* ldstp1;
  if (tid < 256) {
    const int kr = tid >> 3, kc = (tid & 7) * 8;
    gsrc = K + base + (size_t)kr * 64 + (kc ^ ((kr & 7) * 8));
    ldstp0 = &Kl[0][kr * 64 + kc];
    ldstp1 = &Kl[1][kr * 64 + kc];
  } else {
    const int T = tid - 256;
    const int vd = T >> 2, vc = (T & 3) * 8;
    gsrc = Vt + base + (size_t)vd * 2048 + (vc ^ ((vd & 3) * 8));
    ldstp0 = &Vl[0][vd * 32 + vc];
    ldstp1 = &Vl[1][vd * 32 + vc];
  }
  const size_t kstep = (tid < 256) ? 64 : 1;  // per-key-index element stride
  // prologue: tiles 0 and 1
  gload16(gsrc, ldstp0);
  gload16(gsrc + 32 * kstep, ldstp1);
  f32x4 lacc = {};
  f32x4 o[4] = {};
  for (int kt = 0; kt <= ktlim; ++kt) {
    const int c = kt & 1;
    const int k0 = kt * 32;
    if (kt < ktlim)
      asm volatile("s_waitcnt vmcnt(1)" ::: "memory");
    else
      asm volatile("s_waitcnt vmcnt(0)" ::: "memory");
    __builtin_amdgcn_s_barrier();  // tile kt landed for all waves
    if (kt <= ktmax) {
      const bool needmask = (k0 + 31 > qw);  // wave-uniform
      __builtin_amdgcn_s_setprio(1);
#pragma unroll
      for (int n = 0; n < 2; ++n) {
        f32x4 s = {};
#pragma unroll
        for (int kk = 0; kk < 2; ++kk) {
          bf16x8 kf = *reinterpret_cast<const bf16x8*>(
              &Kl[c][(n * 16 + col) * 64 + ((g * 8 + kk * 32) ^ swc)]);
          s = MFMA16(kf, qf[kk], s);
        }
        if (needmask) {
#pragma unroll
          for (int r = 0; r < 4; ++r)
            if (k0 + n * 16 + g * 4 + r > q) s[r] = -3e38f;
        }
        alignas(8) bf16 t[4];
#pragma unroll
        for (int r = 0; r < 4; ++r) {
          float p = exp2f(s[r]);
          lacc[r] += p;
          t[r] = __float2bfloat16(p);
        }
        *reinterpret_cast<uint2*>(&Pl[wave * 16 + col][n * 16 + g * 4]) =
            *reinterpret_cast<uint2*>(t);
      }
      // O += P V   (single K=32 MFMA per n2)
      {
        bf16x8 pf = *reinterpret_cast<const bf16x8*>(&Pl[wave * 16 + col][g * 8]);
#pragma unroll
        for (int n2 = 0; n2 < 4; ++n2) {
          bf16x8 vf = *reinterpret_cast<const bf16x8*>(
              &Vl[c][(n2 * 16 + col) * 32 + ((g * 8) ^ vwc)]);
          o[n2] = MFMA16(pf, vf, o[n2]);
        }
      }
      __builtin_amdgcn_s_setprio(0);
    }
    __builtin_amdgcn_s_barrier();  // all waves done reading buf c
    if (kt + 2 <= ktlim) gload16(gsrc + (size_t)(k0 + 64) * kstep, c ? ldstp1 : ldstp0);
  }
  float l_s = lacc[0] + lacc[1] + lacc[2] + lacc[3];
  l_s += __shfl_xor(l_s, 16);
  l_s += __shfl_xor(l_s, 32);
#pragma unroll
  for (int r = 0; r < 4; ++r) {
    float inv = 1.0f / __shfl(l_s, (lane & 48) | (g * 4 + r));
    int s = qw + g * 4 + r;
#pragma unroll
    for (int n2 = 0; n2 < 4; ++n2)
      AO[((size_t)(b * 2048 + s) << 10) + h * 64 + n2 * 16 + col] =
          __float2bfloat16(o[n2][r] * inv);
  }
}

// ---------------------------------------------------------------- out projection (R13: interleaved counted-vmcnt)
__global__ __launch_bounds__(512) void k_outproj(const bf16* __restrict__ A,
                                                 const bf16* __restrict__ W,
                                                 float* __restrict__ OUT) {
  __shared__ bf16 Al[2][128 * 64];
  __shared__ bf16 Bl[2][256 * 64];
  const int tid = threadIdx.x;
  const int wid = tid >> 6, lane = tid & 63, col = lane & 15, g = lane >> 4;
  const int wr = wid >> 2, wc = wid & 3;
  const int m0 = blockIdx.x * 128, n0 = blockIdx.y * 256;
  const int srow = tid >> 3;
  const int scol = (tid & 7) * 8;
  const int csrc = scol ^ ((srow & 7) * 8);
  const bf16* ga = A + (size_t)(m0 + srow) * 1024 + csrc;
  const bf16* gb = W + (size_t)(n0 + srow) * 1024 + csrc;
  const int ldst = srow * 64 + scol;
  const int rsw = (col & 7) * 8;
  f32x4 acc[4][4] = {};
#define OP_STAGE_ALL(buf, k0)                                \
  do {                                                       \
    gload16(ga + (k0), &Al[buf][ldst]);                      \
    gload16(ga + (k0) + 64 * 1024, &Al[buf][ldst + 4096]);   \
    gload16(gb + (k0), &Bl[buf][ldst]);                      \
    gload16(gb + (k0) + 64 * 1024, &Bl[buf][ldst + 4096]);   \
    gload16(gb + (k0) + 128 * 1024, &Bl[buf][ldst + 8192]);  \
    gload16(gb + (k0) + 192 * 1024, &Bl[buf][ldst + 12288]); \
  } while (0)
  OP_STAGE_ALL(0, 0);
  OP_STAGE_ALL(1, 64);
  for (int kt = 0; kt < 16; ++kt) {
    const int c = kt & 1;
    if (kt < 15)
      asm volatile("s_waitcnt vmcnt(6)" ::: "memory");
    else
      asm volatile("s_waitcnt vmcnt(0)" ::: "memory");
    __builtin_amdgcn_s_barrier();
    const bf16* Ac = Al[c];
    const bf16* Bc = Bl[c];
    bf16x8 af[2][4], bfr[2][4];
#pragma unroll
    for (int kk = 0; kk < 2; ++kk) {
      const int ce = (kk * 32 + g * 8) ^ rsw;
#pragma unroll
      for (int m = 0; m < 4; ++m)
        af[kk][m] =
            *reinterpret_cast<const bf16x8*>(&Ac[(wr * 64 + m * 16 + col) * 64 + ce]);
#pragma unroll
      for (int n = 0; n < 4; ++n)
        bfr[kk][n] =
            *reinterpret_cast<const bf16x8*>(&Bc[(wc * 64 + n * 16 + col) * 64 + ce]);
    }
    __builtin_amdgcn_s_setprio(1);
#pragma unroll
    for (int m = 0; m < 4; ++m) {
      acc[m][0] = MFMA16(af[0][m], bfr[0][0], acc[m][0]);
      acc[m][1] = MFMA16(af[0][m], bfr[0][1], acc[m][1]);
    }
    __builtin_amdgcn_s_setprio(0);
    asm volatile("s_waitcnt lgkmcnt(0)" ::: "memory");
    __builtin_amdgcn_sched_barrier(0);
    __builtin_amdgcn_s_barrier();
    const bool more = (kt + 2 < 16);
    const int k2 = (kt + 2) * 64;
    if (more) {
      gload16(ga + k2, &Al[c][ldst]);
      gload16(ga + k2 + 64 * 1024, &Al[c][ldst + 4096]);
    }
    __builtin_amdgcn_s_setprio(1);
#pragma unroll
    for (int m = 0; m < 4; ++m) {
      acc[m][2] = MFMA16(af[0][m], bfr[0][2], acc[m][2]);
      acc[m][3] = MFMA16(af[0][m], bfr[0][3], acc[m][3]);
    }
    __builtin_amdgcn_s_setprio(0);
    if (more) {
      gload16(gb + k2, &Bl[c][ldst]);
      gload16(gb + k2 + 64 * 1024, &Bl[c][ldst + 4096]);
    }
    __builtin_amdgcn_s_setprio(1);
#pragma unroll
    for (int m = 0; m < 4; ++m) {
      acc[m][0] = MFMA16(af[1][m], bfr[1][0], acc[m][0]);
      acc[m][1] = MFMA16(af[1][m], bfr[1][1], acc[m][1]);
    }
    __builtin_amdgcn_s_setprio(0);
    if (more) {
      gload16(gb + k2 + 128 * 1024, &Bl[c][ldst + 8192]);
      gload16(gb + k2 + 192 * 1024, &Bl[c][ldst + 12288]);
    }
    __builtin_amdgcn_s_setprio(1);
#pragma unroll
    for (int m = 0; m < 4; ++m) {
      acc[m][2] = MFMA16(af[1][m], bfr[1][2], acc[m][2]);
      acc[m][3] = MFMA16(af[1][m], bfr[1][3], acc[m][3]);
    }
    __builtin_amdgcn_s_setprio(0);
  }
#undef OP_STAGE_ALL
#pragma unroll
  for (int m = 0; m < 4; ++m)
#pragma unroll
    for (int n = 0; n < 4; ++n)
#pragma unroll
      for (int r = 0; r < 4; ++r)
        OUT[(size_t)(m0 + wr * 64 + m * 16 + g * 4 + r) * 1024 + n0 + wc * 64 + n * 16 +
            col] = acc[m][n][r];
}

// ---------------------------------------------------------------- launcher
extern "C" void kernel_launch(void* const* d_in, const int* in_sizes, int n_in,
                              void* d_out, int out_size, void* d_ws, size_t ws_size,
                              hipStream_t stream) {
  const float* x = (const float*)d_in[0];
  const float* wqkv = (const float*)d_in[1];
  const float* wout = (const float*)d_in[2];
  float* out = (float*)d_out;

  char* ws = (char*)d_ws;
  const size_t SZ_X = (size_t)B_ * S_ * D_ * 2;
  const size_t SZ_WQKV = (size_t)3 * D_ * D_ * 2;
  const size_t SZ_WOUT = (size_t)D_ * D_ * 2;
  const size_t SZ_T = (size_t)B_ * H_ * S_ * HD_ * 2;
  bf16* xb = (bf16*)(ws);
  bf16* wqkvb = (bf16*)(ws + SZ_X);
  bf16* woutb = (bf16*)(ws + SZ_X + SZ_WQKV);
  bf16* qws = (bf16*)(ws + SZ_X + SZ_WQKV + SZ_WOUT);
  bf16* kws = (bf16*)(ws + SZ_X + SZ_WQKV + SZ_WOUT + SZ_T);
  bf16* vtws = (bf16*)(ws + SZ_X + SZ_WQKV + SZ_WOUT + 2 * SZ_T);
  bf16* aob = (bf16*)(ws + SZ_X + SZ_WQKV + SZ_WOUT + 3 * SZ_T);

  const int NTOT4 = (NX_ + NW1_ + NW2_) / 4;
  k_cvt3<<<NTOT4 / 256, 256, 0, stream>>>(x, wqkv, wout, xb, wqkvb, woutb);

  k_qkv<<<dim3(64, 12), 512, 0, stream>>>(xb, wqkvb, qws, kws, vtws);
  k_attn<<<dim3(B_ * H_, 16), 512, 0, stream>>>(qws, kws, vtws, aob);
  k_outproj<<<dim3(64, 4), 512, 0, stream>>>(aob, woutb, out);
}